// Round 10
// baseline (76.499 us; speedup 1.0000x reference)
//
#include <hip/hip_runtime.h>

typedef unsigned short ushort_t;
typedef unsigned int uint_t;
typedef __bf16 bf16x8 __attribute__((ext_vector_type(8)));
typedef float f32x4 __attribute__((ext_vector_type(4)));

#define H 256
#define RPB 32      // batch rows per PAIR
#define PAIRS 128
#define NBLK 256    // 2 blocks per pair

// output layout (f32): [nb 4096][bdot 4096][y 4096*256][yy 4096*64]
#define NB_OFF 0
#define BDOT_OFF 4096
#define Y_OFF 8192
#define YY_OFF (8192 + 4096 * 256)

__device__ __forceinline__ ushort_t f2bf(float x) {
    union { float f; uint_t u; } c; c.f = x;
    uint_t r = (c.u + 0x7FFFu + ((c.u >> 16) & 1u)) >> 16;  // RNE
    return (ushort_t)r;
}
__device__ __forceinline__ float bf2f(ushort_t v) {
    union { uint_t u; float f; } c; c.u = ((uint_t)v) << 16;
    return c.f;
}

// ws layout (ushort units)
#define O_W1b  0        // [256][64]  orig
#define O_W1T  16384    // [64][256]
#define O_W2ab 32768    // [256][256] orig
#define O_W2bb 98304
#define O_W3ab 163840
#define O_W2aT 229376
#define O_W2bT 294912
#define O_W3aT 360448   // wout folded
#define O_W3sb 425984   // [256][64]
#define O_W3sT 442368   // wout folded
// exchange region
#define X_EX   458752
#define PXU    61440    // ushorts per pair
#define EX_Y1  0        // bf16 [32][256]
#define EX_Z23 8192     // bf16
#define EX_Z22 16384    // bf16
#define EX_T   24576    // bf16
#define EX_Z13 32768    // bf16
#define EX_PO  40960    // f32 [32][256] = 16384 ushorts
#define EX_FJ  57344    // f32 [32][64]  = 4096 ushorts
#define X_FLAG (X_EX + PAIRS * PXU)   // int flags[PAIRS][8]
// flag ids
#define FE1 0
#define FE2 1
#define FO2 2
#define FO3 3
#define FO4 4
#define FO5 5

__global__ __launch_bounds__(256) void prep_weights(
    const float* __restrict__ w1, const float* __restrict__ w2a,
    const float* __restrict__ w2b, const float* __restrict__ w3a,
    const float* __restrict__ w3s, const float* __restrict__ wout,
    ushort_t* __restrict__ ws) {
    int b = blockIdx.x;
    const int tid = threadIdx.x;
    if (b == 112) {  // zero pair flags for this launch
        int* fl = (int*)(ws + X_FLAG);
        for (int i = tid; i < PAIRS * 8; i += 256) fl[i] = 0;
        return;
    }
    __shared__ float tile[32][65];
    const float* src; int Oo, Ot, C, t; bool scl;
    if (b < 32)       { src = w2a; Oo = O_W2ab; Ot = O_W2aT; C = 256; t = b;       scl = false; }
    else if (b < 64)  { src = w2b; Oo = O_W2bb; Ot = O_W2bT; C = 256; t = b - 32;  scl = false; }
    else if (b < 96)  { src = w3a; Oo = O_W3ab; Ot = O_W3aT; C = 256; t = b - 64;  scl = true;  }
    else if (b < 104) { src = w1;  Oo = O_W1b;  Ot = O_W1T;  C = 64;  t = b - 96;  scl = false; }
    else              { src = w3s; Oo = O_W3sb; Ot = O_W3sT; C = 64;  t = b - 104; scl = true;  }
    int tr, tc;
    if (C == 256) { tr = t >> 2; tc = t & 3; } else { tr = t; tc = 0; }
    int r0 = tr * 32, c0 = tc * 64;

    union pack8 { ushort_t u[8]; uint4 q; };
    {
        int r = tid >> 3, c8 = (tid & 7) << 3;
        const float* s = src + (r0 + r) * C + c0 + c8;
        pack8 p;
#pragma unroll
        for (int j = 0; j < 8; j++) { float v = s[j]; tile[r][c8 + j] = v; p.u[j] = f2bf(v); }
        *(uint4*)(ws + Oo + (r0 + r) * C + c0 + c8) = p.q;
    }
    __syncthreads();
    {
        int cc = tid >> 2, r8 = (tid & 3) << 3;
        pack8 p;
#pragma unroll
        for (int j = 0; j < 8; j++) {
            float v = tile[r8 + j][cc];
            if (scl) v *= wout[r0 + r8 + j];
            p.u[j] = f2bf(v);
        }
        *(uint4*)(ws + Ot + (c0 + cc) * 256 + r0 + r8) = p.q;
    }
}

// dynamic smem (ushort units)
#define U_RING 0        // 16 waves * 4 slots * 512 = 32768 (aliased by FJ f32[4][2048] in P7+)
#define U_B0   32768    // 8192: E: y1->y2   | O: y1recv -> z13recv
#define U_B1   40960    // 8192: E: z1_2->tz1->c2 | O: z2_3
#define U_B2   49152    // 8192: O: z2_2->tz2
#define U_XD   57344    // f32 [2048]
#define U_NB   61440    // f32 [32]
#define SMEM_USHORTS 61504
#define SMEM_BYTES (SMEM_USHORTS * 2)

__device__ __forceinline__ void gload16(const ushort_t* g, ushort_t* l) {
    __builtin_amdgcn_global_load_lds(
        (const __attribute__((address_space(1))) void*)g,
        (__attribute__((address_space(3))) void*)l, 16, 0, 0);
}

template <int N> __device__ __forceinline__ void vwait() {
    if constexpr (N == 3) asm volatile("s_waitcnt vmcnt(3)" ::: "memory");
    else if constexpr (N == 2) asm volatile("s_waitcnt vmcnt(2)" ::: "memory");
    else if constexpr (N == 1) asm volatile("s_waitcnt vmcnt(1)" ::: "memory");
    else asm volatile("s_waitcnt vmcnt(0)" ::: "memory");
}

#define PHASE_BARRIER() do { \
    asm volatile("s_waitcnt lgkmcnt(0)" ::: "memory"); \
    __builtin_amdgcn_sched_barrier(0); \
    __builtin_amdgcn_s_barrier(); \
    __builtin_amdgcn_sched_barrier(0); \
} while (0)

__device__ __forceinline__ void post_flag(int* f) {
    __syncthreads();  // all stores drained (vmcnt0 at barrier)
    if (threadIdx.x == 0)
        __hip_atomic_store(f, 1, __ATOMIC_RELEASE, __HIP_MEMORY_SCOPE_AGENT);
}
__device__ __forceinline__ void wait_flag(int* f) {
    if (threadIdx.x == 0) {
        while (__hip_atomic_load(f, __ATOMIC_ACQUIRE, __HIP_MEMORY_SCOPE_AGENT) == 0)
            __builtin_amdgcn_s_sleep(2);
    }
    __syncthreads();
}

__device__ __forceinline__ int posw(int r, int c) { return r * H + (c ^ ((r & 7) << 3)); }

// 8-unit ring sub-phase (one matrix, K=256 in 8 chunks). Global unit u=PH*8+k,
// slot u&3, restage unit u+4 into the slot just read (guarded lgkmcnt(2)).
// mA/mB/mC = the block's three staged matrices in stream order.
template <int PH>
__device__ __forceinline__ void ring8(
    const ushort_t* __restrict__ mA, const ushort_t* __restrict__ mB,
    const ushort_t* __restrict__ mC,
    const ushort_t* aM, ushort_t* rw, int srcoff, int boff, int row16,
    int kq, int sw, f32x4& acc0, f32x4& acc1) {
    const int arow0 = row16 * H;
    const int arow1 = arow0 + 16 * H;
#pragma unroll
    for (int k = 0; k < 8; ++k) {
        const int u = PH * 8 + k;
        if (PH == 2) {
            if (k < 5) vwait<3>();
            else if (k == 5) vwait<2>();
            else if (k == 6) vwait<1>();
            else vwait<0>();
        } else {
            vwait<3>();
        }
        __builtin_amdgcn_sched_barrier(0);
        bf16x8 b = *(const bf16x8*)(rw + (u & 3) * 512 + boff);
        const int ko = ((k << 5) + kq) ^ sw;
        bf16x8 a0 = *(const bf16x8*)(aM + arow0 + ko);
        bf16x8 a1 = *(const bf16x8*)(aM + arow1 + ko);
        if (u + 4 < 24) {
            asm volatile("s_waitcnt lgkmcnt(2)" ::: "memory");
            __builtin_amdgcn_sched_barrier(0);
            const int u4 = u + 4;
            const ushort_t* g = (u4 < 8) ? mA : (u4 < 16) ? mB : mC;
            gload16(g + srcoff + ((u4 & 7) << 5), rw + (u4 & 3) * 512);
        }
        acc0 = __builtin_amdgcn_mfma_f32_16x16x32_bf16(a0, b, acc0, 0, 0, 0);
        acc1 = __builtin_amdgcn_mfma_f32_16x16x32_bf16(a1, b, acc1, 0, 0, 0);
    }
}

// register-path tile GEMM (small matrices)
template <int NF, int STRA, int STRB>
__device__ __forceinline__ void gemm_one(const ushort_t* sA, const ushort_t* __restrict__ B0,
                                         int lane, int k0, f32x4& acc0) {
    const int row = lane & 15;
    const int kq = (lane >> 4) << 3;
    const int sw = (row & 7) << 3;
    bf16x8 b0[NF], a[NF];
    const ushort_t* bp0 = B0 + row * STRB + k0 + kq;
    const ushort_t* ap = sA + row * STRA;
#pragma unroll
    for (int i = 0; i < NF; i++) b0[i] = *(const bf16x8*)(bp0 + i * 32);
#pragma unroll
    for (int i = 0; i < NF; i++) a[i] = *(const bf16x8*)(ap + ((k0 + i * 32 + kq) ^ sw));
    __builtin_amdgcn_sched_barrier(0);
#pragma unroll
    for (int i = 0; i < NF; i++)
        acc0 = __builtin_amdgcn_mfma_f32_16x16x32_bf16(a[i], b0[i], acc0, 0, 0, 0);
}

__global__ __launch_bounds__(1024) void net_main(
    const float* __restrict__ x, const float* __restrict__ xd,
    const float* __restrict__ b1, const float* __restrict__ b2a,
    const float* __restrict__ b2b, const float* __restrict__ b3a,
    const float* __restrict__ b3s, const float* __restrict__ wout,
    const float* __restrict__ scalar, ushort_t* __restrict__ ws,
    float* __restrict__ out) {
    extern __shared__ __align__(16) ushort_t smem[];
    ushort_t* sB0 = smem + U_B0;
    ushort_t* sB1 = smem + U_B1;
    ushort_t* sB2 = smem + U_B2;
    float* sXd = (float*)(smem + U_XD);
    float* sNB = (float*)(smem + U_NB);
    float* sFJ = (float*)smem;  // aliases ring (dead after P6)

    const int tid = threadIdx.x;
    const int wid = tid >> 6;
    const int lane = tid & 63;
    const int row16 = lane & 15;
    const int rq = lane >> 4;
    const bool isE = blockIdx.x < PAIRS;
    const int pid = blockIdx.x & (PAIRS - 1);
    const int R0 = pid * RPB;
    const int n0 = wid * 16;
    const int kq = rq << 3;
    const int sw = (row16 & 7) << 3;

    ushort_t* rw = smem + U_RING + wid * 2048;
    const int nsrc = (wid << 4) + (lane >> 2);
    const int srcoff = nsrc * 256 + (((lane & 3) ^ (nsrc & 3)) << 3);
    const int boff = row16 * 32 + (kq ^ ((row16 & 3) << 3));

    ushort_t* ex = ws + X_EX + pid * PXU;
    int* fl = (int*)(ws + X_FLAG) + pid * 8;

    const int c = n0 + row16;

    if (isE) {
        const ushort_t* m0 = ws + O_W2ab;
        const ushort_t* m1 = ws + O_W3ab;
        const ushort_t* m2 = ws + O_W2bT;
        f32x4 zk0, zk1;
        // ---- P1: ring prologue + z = x@W1.T + b1; y1 = z^2
        {
            const ushort_t* w1p = ws + O_W1b + c * 64 + kq;
            bf16x8 pb0 = *(const bf16x8*)(w1p);
            bf16x8 pb1 = *(const bf16x8*)(w1p + 32);
            const float* xg0 = x + (R0 + row16) * 64;
            const float* xg1 = x + (R0 + 16 + row16) * 64;
            float4 xa0 = *(const float4*)(xg0 + kq);
            float4 xa1 = *(const float4*)(xg0 + kq + 4);
            float4 xa2 = *(const float4*)(xg0 + 32 + kq);
            float4 xa3 = *(const float4*)(xg0 + 32 + kq + 4);
            float4 xb0 = *(const float4*)(xg1 + kq);
            float4 xb1 = *(const float4*)(xg1 + kq + 4);
            float4 xb2 = *(const float4*)(xg1 + 32 + kq);
            float4 xb3 = *(const float4*)(xg1 + 32 + kq + 4);
            gload16(m0 + srcoff, rw);
            gload16(m0 + srcoff + 32, rw + 512);
            gload16(m0 + srcoff + 64, rw + 1024);
            gload16(m0 + srcoff + 96, rw + 1536);
            float sc = scalar[0];
            {
                int xr = tid >> 6, xc = tid & 63;
                sXd[tid] = xd[(R0 + xr) * 64 + xc];
                sXd[tid + 1024] = xd[(R0 + 16 + xr) * 64 + xc];
                out[YY_OFF + (R0 + xr) * 64 + xc] = sc;
                out[YY_OFF + (R0 + 16 + xr) * 64 + xc] = sc;
                if (tid < RPB) sNB[tid] = 0.f;
            }
            union { ushort_t u[8]; bf16x8 v; } A0, A1, B0, B1;
#pragma unroll
            for (int j = 0; j < 4; j++) {
                A0.u[j] = f2bf(((const float*)&xa0)[j]);
                A0.u[4 + j] = f2bf(((const float*)&xa1)[j]);
                A1.u[j] = f2bf(((const float*)&xa2)[j]);
                A1.u[4 + j] = f2bf(((const float*)&xa3)[j]);
                B0.u[j] = f2bf(((const float*)&xb0)[j]);
                B0.u[4 + j] = f2bf(((const float*)&xb1)[j]);
                B1.u[j] = f2bf(((const float*)&xb2)[j]);
                B1.u[4 + j] = f2bf(((const float*)&xb3)[j]);
            }
            f32x4 z0 = {0.f,0.f,0.f,0.f}, z1 = {0.f,0.f,0.f,0.f};
            z0 = __builtin_amdgcn_mfma_f32_16x16x32_bf16(A0.v, pb0, z0, 0, 0, 0);
            z0 = __builtin_amdgcn_mfma_f32_16x16x32_bf16(A1.v, pb1, z0, 0, 0, 0);
            z1 = __builtin_amdgcn_mfma_f32_16x16x32_bf16(B0.v, pb0, z1, 0, 0, 0);
            z1 = __builtin_amdgcn_mfma_f32_16x16x32_bf16(B1.v, pb1, z1, 0, 0, 0);
            float bz = b1[c];
#pragma unroll
            for (int i = 0; i < 4; i++) {
                int r = rq * 4 + i;
                float za = z0[i] + bz, zb = z1[i] + bz;
                zk0[i] = za; zk1[i] = zb;
                ushort_t ya = f2bf(za * za), yb = f2bf(zb * zb);
                sB0[posw(r, c)] = ya; sB0[posw(r + 16, c)] = yb;
                ex[EX_Y1 + r * H + c] = ya;
                ex[EX_Y1 + (r + 16) * H + c] = yb;
            }
        }
        post_flag(fl + FE1);

        // ---- P2: z1_2 = y1@W2a.T + b2a
        {
            f32x4 a0 = {0.f,0.f,0.f,0.f}, a1 = {0.f,0.f,0.f,0.f};
            ring8<0>(m0, m1, m2, sB0, rw, srcoff, boff, row16, kq, sw, a0, a1);
            float ba = b2a[c];
#pragma unroll
            for (int i = 0; i < 4; i++) {
                int r = rq * 4 + i;
                sB1[posw(r, c)] = f2bf(a0[i] + ba);
                sB1[posw(r + 16, c)] = f2bf(a1[i] + ba);
            }
        }
        PHASE_BARRIER();
        wait_flag(fl + FO2);
        // y2 = z1_2 * z2_2recv -> sB0
        for (int e = tid; e < RPB * H; e += 1024) {
            int r = e >> 8, cc2 = e & 255;
            float z22 = bf2f(ex[EX_Z22 + e]);
            int p = posw(r, cc2);
            sB0[p] = f2bf(bf2f(sB1[p]) * z22);
        }
        PHASE_BARRIER();

        // ---- P4: z1_3 = y2@W3a.T + b3a; y3, nb; post z1_3
        f32x4 y3k0, y3k1;
        {
            f32x4 z0 = {0.f,0.f,0.f,0.f}, z1 = {0.f,0.f,0.f,0.f};
            ring8<1>(m0, m1, m2, sB0, rw, srcoff, boff, row16, kq, sw, z0, z1);
            float ba = b3a[c], wo = wout[c];
#pragma unroll
            for (int i = 0; i < 4; i++) {
                int r = rq * 4 + i;
                float z13a = z0[i] + ba, z13b = z1[i] + ba;
                float z23a = bf2f(ex[EX_Z23 + r * H + c]);
                float z23b = bf2f(ex[EX_Z23 + (r + 16) * H + c]);
                float y3a = z13a * z23a, y3b = z13b * z23b;
                y3k0[i] = y3a; y3k1[i] = y3b;
                out[Y_OFF + (R0 + r) * H + c] = y3a;
                out[Y_OFF + (R0 + 16 + r) * H + c] = y3b;
                ex[EX_Z13 + r * H + c] = f2bf(z13a);
                ex[EX_Z13 + (r + 16) * H + c] = f2bf(z13b);
                float v0 = wo * y3a, v1 = wo * y3b;
                v0 += __shfl_xor(v0, 1); v0 += __shfl_xor(v0, 2);
                v0 += __shfl_xor(v0, 4); v0 += __shfl_xor(v0, 8);
                v1 += __shfl_xor(v1, 1); v1 += __shfl_xor(v1, 2);
                v1 += __shfl_xor(v1, 4); v1 += __shfl_xor(v1, 8);
                if (row16 == 0) { atomicAdd(&sNB[r], v0); atomicAdd(&sNB[r + 16], v1); }
            }
        }
        post_flag(fl + FE2);
        wait_flag(fl + FO3);
        // tz1 = t_recv * z1_2 (own positions)
        {
#pragma unroll
            for (int i = 0; i < 4; i++) {
                int r = rq * 4 + i;
                int p0 = posw(r, c), p1 = posw(r + 16, c);
                float t0 = bf2f(ex[EX_T + r * H + c]);
                float t1 = bf2f(ex[EX_T + (r + 16) * H + c]);
                sB1[p0] = f2bf(t0 * bf2f(sB1[p0]));
                sB1[p1] = f2bf(t1 * bf2f(sB1[p1]));
            }
        }
        PHASE_BARRIER();

        // ---- P6: pE = tz1@W2bT ; c2 = 2*(pE+pO)*z -> sB1
        {
            f32x4 p0 = {0.f,0.f,0.f,0.f}, p1 = {0.f,0.f,0.f,0.f};
            ring8<2>(m0, m1, m2, sB1, rw, srcoff, boff, row16, kq, sw, p0, p1);
            wait_flag(fl + FO4);
            const float* poF = (const float*)(ex + EX_PO);
#pragma unroll
            for (int i = 0; i < 4; i++) {
                int r = rq * 4 + i;
                float pa = p0[i] + poF[r * H + c];
                float pb = p1[i] + poF[(r + 16) * H + c];
                sB1[posw(r, c)] = f2bf(2.f * pa * zk0[i]);
                sB1[posw(r + 16, c)] = f2bf(2.f * pb * zk1[i]);
            }
        }
        PHASE_BARRIER();

        // ---- P7: fj2 = c2@W1T (nt x kh split over 16 waves) -> sFJ (ring area)
        {
            int nt = wid & 3, kh = wid >> 2;
            const ushort_t* B = ws + O_W1T + nt * 16 * H;
            int cc2 = nt * 16 + row16;
#pragma unroll
            for (int rg = 0; rg < 2; rg++) {
                f32x4 acc = {0.f,0.f,0.f,0.f};
                gemm_one<2, H, H>(sB1 + rg * 16 * H, B, lane, kh * 64, acc);
#pragma unroll
                for (int i = 0; i < 4; i++)
                    sFJ[kh * 2048 + (rg * 16 + rq * 4 + i) * 64 + cc2] = acc[i];
            }
        }
        PHASE_BARRIER();
        wait_flag(fl + FO5);
        // ---- P8: bdot + nb
        {
            const float* fjO = (const float*)(ex + EX_FJ);
            int r = tid >> 5, j = tid & 31;
            int e = r * 64 + j, e2 = e + 32;
            float s = (sFJ[e] + sFJ[2048 + e] + sFJ[4096 + e] + sFJ[6144 + e] + fjO[e]) * sXd[e] +
                      (sFJ[e2] + sFJ[2048 + e2] + sFJ[4096 + e2] + sFJ[6144 + e2] + fjO[e2]) * sXd[e2];
            s += __shfl_xor(s, 1);
            s += __shfl_xor(s, 2);
            s += __shfl_xor(s, 4);
            s += __shfl_xor(s, 8);
            s += __shfl_xor(s, 16);
            if (j == 0) out[BDOT_OFF + R0 + r] = s;
            if (tid < RPB) out[NB_OFF + R0 + tid] = sNB[tid];
        }
    } else {
        // ---------------- O role ----------------
        const ushort_t* m0 = ws + O_W2bb;
        const ushort_t* m1 = ws + O_W3aT;
        const ushort_t* m2 = ws + O_W2aT;
        // ---- P1: ring prologue + z2_3 = x@W3s.T + b3s
        {
            const ushort_t* w3p = ws + O_W3sb + c * 64 + kq;
            bf16x8 pb0 = *(const bf16x8*)(w3p);
            bf16x8 pb1 = *(const bf16x8*)(w3p + 32);
            const float* xg0 = x + (R0 + row16) * 64;
            const float* xg1 = x + (R0 + 16 + row16) * 64;
            float4 xa0 = *(const float4*)(xg0 + kq);
            float4 xa1 = *(const float4*)(xg0 + kq + 4);
            float4 xa2 = *(const float4*)(xg0 + 32 + kq);
            float4 xa3 = *(const float4*)(xg0 + 32 + kq + 4);
            float4 xb0 = *(const float4*)(xg1 + kq);
            float4 xb1 = *(const float4*)(xg1 + kq + 4);
            float4 xb2 = *(const float4*)(xg1 + 32 + kq);
            float4 xb3 = *(const float4*)(xg1 + 32 + kq + 4);
            gload16(m0 + srcoff, rw);
            gload16(m0 + srcoff + 32, rw + 512);
            gload16(m0 + srcoff + 64, rw + 1024);
            gload16(m0 + srcoff + 96, rw + 1536);
            union { ushort_t u[8]; bf16x8 v; } A0, A1, B0, B1;
#pragma unroll
            for (int j = 0; j < 4; j++) {
                A0.u[j] = f2bf(((const float*)&xa0)[j]);
                A0.u[4 + j] = f2bf(((const float*)&xa1)[j]);
                A1.u[j] = f2bf(((const float*)&xa2)[j]);
                A1.u[4 + j] = f2bf(((const float*)&xa3)[j]);
                B0.u[j] = f2bf(((const float*)&xb0)[j]);
                B0.u[4 + j] = f2bf(((const float*)&xb1)[j]);
                B1.u[j] = f2bf(((const float*)&xb2)[j]);
                B1.u[4 + j] = f2bf(((const float*)&xb3)[j]);
            }
            f32x4 q0 = {0.f,0.f,0.f,0.f}, q1 = {0.f,0.f,0.f,0.f};
            q0 = __builtin_amdgcn_mfma_f32_16x16x32_bf16(A0.v, pb0, q0, 0, 0, 0);
            q0 = __builtin_amdgcn_mfma_f32_16x16x32_bf16(A1.v, pb1, q0, 0, 0, 0);
            q1 = __builtin_amdgcn_mfma_f32_16x16x32_bf16(B0.v, pb0, q1, 0, 0, 0);
            q1 = __builtin_amdgcn_mfma_f32_16x16x32_bf16(B1.v, pb1, q1, 0, 0, 0);
            float bs = b3s[c];
#pragma unroll
            for (int i = 0; i < 4; i++) {
                int r = rq * 4 + i;
                ushort_t va = f2bf(q0[i] + bs), vb = f2bf(q1[i] + bs);
                sB1[posw(r, c)] = va; sB1[posw(r + 16, c)] = vb;
                ex[EX_Z23 + r * H + c] = va;
                ex[EX_Z23 + (r + 16) * H + c] = vb;
            }
        }
        wait_flag(fl + FE1);
        // copy y1recv -> sB0 (posw)
        for (int e = tid; e < RPB * H; e += 1024) {
            int r = e >> 8, cc2 = e & 255;
            sB0[posw(r, cc2)] = ex[EX_Y1 + e];
        }
        PHASE_BARRIER();

        // ---- P2: z2_2 = y1@W2b.T + b2b
        {
            f32x4 a0 = {0.f,0.f,0.f,0.f}, a1 = {0.f,0.f,0.f,0.f};
            ring8<0>(m0, m1, m2, sB0, rw, srcoff, boff, row16, kq, sw, a0, a1);
            float bb = b2b[c];
#pragma unroll
            for (int i = 0; i < 4; i++) {
                int r = rq * 4 + i;
                ushort_t va = f2bf(a0[i] + bb), vb = f2bf(a1[i] + bb);
                sB2[posw(r, c)] = va; sB2[posw(r + 16, c)] = vb;
                ex[EX_Z22 + r * H + c] = va;
                ex[EX_Z22 + (r + 16) * H + c] = vb;
            }
        }
        post_flag(fl + FO2);
        PHASE_BARRIER();

        // ---- P4: t = z2_3@(wout.w3a)T ; post t; tz2 = t*z2_2
        {
            f32x4 t0 = {0.f,0.f,0.f,0.f}, t1 = {0.f,0.f,0.f,0.f};
            ring8<1>(m0, m1, m2, sB1, rw, srcoff, boff, row16, kq, sw, t0, t1);
#pragma unroll
            for (int i = 0; i < 4; i++) {
                int r = rq * 4 + i;
                ex[EX_T + r * H + c] = f2bf(t0[i]);
                ex[EX_T + (r + 16) * H + c] = f2bf(t1[i]);
            }
            post_flag(fl + FO3);
#pragma unroll
            for (int i = 0; i < 4; i++) {
                int r = rq * 4 + i;
                int p0 = posw(r, c), p1 = posw(r + 16, c);
                sB2[p0] = f2bf(t0[i] * bf2f(sB2[p0]));
                sB2[p1] = f2bf(t1[i] * bf2f(sB2[p1]));
            }
        }
        PHASE_BARRIER();

        // ---- P6: pO = tz2@W2aT ; post pO (f32)
        {
            f32x4 p0 = {0.f,0.f,0.f,0.f}, p1 = {0.f,0.f,0.f,0.f};
            ring8<2>(m0, m1, m2, sB2, rw, srcoff, boff, row16, kq, sw, p0, p1);
            float* poF = (float*)(ex + EX_PO);
#pragma unroll
            for (int i = 0; i < 4; i++) {
                int r = rq * 4 + i;
                poF[r * H + c] = p0[i];
                poF[(r + 16) * H + c] = p1[i];
            }
        }
        post_flag(fl + FO4);
        wait_flag(fl + FE2);
        // copy z1_3recv -> sB0
        for (int e = tid; e < RPB * H; e += 1024) {
            int r = e >> 8, cc2 = e & 255;
            sB0[posw(r, cc2)] = ex[EX_Z13 + e];
        }
        PHASE_BARRIER();

        // ---- P7: fjO = z1_3@(wout.w3s)T -> sFJ partials
        {
            int nt = wid & 3, kh = wid >> 2;
            const ushort_t* B = ws + O_W3sT + nt * 16 * H;
            int cc2 = nt * 16 + row16;
#pragma unroll
            for (int rg = 0; rg < 2; rg++) {
                f32x4 acc = {0.f,0.f,0.f,0.f};
                gemm_one<2, H, H>(sB0 + rg * 16 * H, B, lane, kh * 64, acc);
#pragma unroll
                for (int i = 0; i < 4; i++)
                    sFJ[kh * 2048 + (rg * 16 + rq * 4 + i) * 64 + cc2] = acc[i];
            }
        }
        PHASE_BARRIER();
        {
            float* fjO = (float*)(ex + EX_FJ);
            for (int e = tid; e < 2048; e += 1024)
                fjO[e] = sFJ[e] + sFJ[2048 + e] + sFJ[4096 + e] + sFJ[6144 + e];
        }
        post_flag(fl + FO5);
    }
}

extern "C" void kernel_launch(void* const* d_in, const int* in_sizes, int n_in,
                              void* d_out, int out_size, void* d_ws, size_t ws_size,
                              hipStream_t stream) {
    (void)in_sizes; (void)n_in; (void)out_size; (void)ws_size;
    const float* x = (const float*)d_in[0];
    const float* xd = (const float*)d_in[1];
    const float* w1 = (const float*)d_in[2];
    const float* b1 = (const float*)d_in[3];
    const float* w2a = (const float*)d_in[4];
    const float* b2a = (const float*)d_in[5];
    const float* w2b = (const float*)d_in[6];
    const float* b2b = (const float*)d_in[7];
    const float* w3a = (const float*)d_in[8];
    const float* b3a = (const float*)d_in[9];
    const float* w3s = (const float*)d_in[10];
    const float* b3s = (const float*)d_in[11];
    const float* wout = (const float*)d_in[12];
    const float* scalar = (const float*)d_in[13];
    ushort_t* ws = (ushort_t*)d_ws;
    float* out = (float*)d_out;

    static bool attr_set = false;
    if (!attr_set) {
        hipFuncSetAttribute((const void*)net_main,
                            hipFuncAttributeMaxDynamicSharedMemorySize, SMEM_BYTES);
        attr_set = true;
    }

    prep_weights<<<113, 256, 0, stream>>>(w1, w2a, w2b, w3a, w3s, wout, ws);
    net_main<<<NBLK, 1024, SMEM_BYTES, stream>>>(x, xd, b1, b2a, b2b, b3a, b3s, wout, scalar, ws, out);
}

// Round 11
// 33.397 us; speedup vs baseline: 2.2906x; 2.2906x over previous
//
#include <hip/hip_runtime.h>

typedef unsigned short ushort_t;
typedef unsigned int uint_t;
typedef __bf16 bf16x8 __attribute__((ext_vector_type(8)));
typedef float f32x4 __attribute__((ext_vector_type(4)));

#define H 256
#define RPB 16      // batch rows per block
#define NBLK 256    // 4096 / RPB

// output layout (f32): [nb 4096][bdot 4096][y 4096*256][yy 4096*64]
#define NB_OFF 0
#define BDOT_OFF 4096
#define Y_OFF 8192
#define YY_OFF (8192 + 4096 * 256)

__device__ __forceinline__ ushort_t f2bf(float x) {
    union { float f; uint_t u; } c; c.f = x;
    uint_t r = (c.u + 0x7FFFu + ((c.u >> 16) & 1u)) >> 16;  // RNE
    return (ushort_t)r;
}
__device__ __forceinline__ float bf2f(ushort_t v) {
    union { uint_t u; float f; } c; c.u = ((uint_t)v) << 16;
    return c.f;
}

// ws layout (ushort/bf16 units)
#define O_W1b  0        // [256][64]   orig (B for z)
#define O_W1T  16384    // [64][256]
#define O_W2ab 32768    // [256][256]  orig
#define O_W2bb 98304
#define O_W3ab 163840
#define O_W2aT 229376
#define O_W2bT 294912
#define O_W3aT 360448   // wout folded
#define O_W3sb 425984   // [256][64]
#define O_W3sT 442368   // wout folded

__global__ __launch_bounds__(256) void prep_weights(
    const float* __restrict__ w1, const float* __restrict__ w2a,
    const float* __restrict__ w2b, const float* __restrict__ w3a,
    const float* __restrict__ w3s, const float* __restrict__ wout,
    ushort_t* __restrict__ ws) {
    __shared__ float tile[32][65];
    int b = blockIdx.x;
    const float* src; int Oo, Ot, C, t; bool scl;
    if (b < 32)       { src = w2a; Oo = O_W2ab; Ot = O_W2aT; C = 256; t = b;       scl = false; }
    else if (b < 64)  { src = w2b; Oo = O_W2bb; Ot = O_W2bT; C = 256; t = b - 32;  scl = false; }
    else if (b < 96)  { src = w3a; Oo = O_W3ab; Ot = O_W3aT; C = 256; t = b - 64;  scl = true;  }
    else if (b < 104) { src = w1;  Oo = O_W1b;  Ot = O_W1T;  C = 64;  t = b - 96;  scl = false; }
    else              { src = w3s; Oo = O_W3sb; Ot = O_W3sT; C = 64;  t = b - 104; scl = true;  }
    int tr, tc;
    if (C == 256) { tr = t >> 2; tc = t & 3; } else { tr = t; tc = 0; }
    int r0 = tr * 32, c0 = tc * 64;
    const int tid = threadIdx.x;

    union pack8 { ushort_t u[8]; uint4 q; };
    {
        int r = tid >> 3, c8 = (tid & 7) << 3;
        const float* s = src + (r0 + r) * C + c0 + c8;
        pack8 p;
#pragma unroll
        for (int j = 0; j < 8; j++) { float v = s[j]; tile[r][c8 + j] = v; p.u[j] = f2bf(v); }
        *(uint4*)(ws + Oo + (r0 + r) * C + c0 + c8) = p.q;
    }
    __syncthreads();
    {
        int cc = tid >> 2, r8 = (tid & 3) << 3;
        pack8 p;
#pragma unroll
        for (int j = 0; j < 8; j++) {
            float v = tile[r8 + j][cc];
            if (scl) v *= wout[r0 + r8 + j];
            p.u[j] = f2bf(v);
        }
        *(uint4*)(ws + Ot + (c0 + cc) * 256 + r0 + r8) = p.q;
    }
}

// dynamic smem layout (ushort units)
#define U_RING 0        // 16 waves * 4 slots * 512 = 32768
#define U_Z    32768    // z -> c2 source
#define U_Y    36864    // y1 -> z1_3
#define U_Z12  40960    // z1_2 -> tz1
#define U_Z22  45056    // z2_2 -> tz2
#define U_Z23  49152    // z2_3; later FJ[0..1] f32
#define U_U    53248    // y2;   later FJ[2..3] f32
#define U_XD   57344    // f32 [1024]
#define U_NB   59392    // f32 [16]
#define SMEM_USHORTS 59424
#define SMEM_BYTES (SMEM_USHORTS * 2)

__device__ __forceinline__ void gload16(const ushort_t* g, ushort_t* l) {
    __builtin_amdgcn_global_load_lds(
        (const __attribute__((address_space(1))) void*)g,
        (__attribute__((address_space(3))) void*)l, 16, 0, 0);
}

template <int N> __device__ __forceinline__ void vwait() {
    if constexpr (N == 4) asm volatile("s_waitcnt vmcnt(4)" ::: "memory");
    else if constexpr (N == 2) asm volatile("s_waitcnt vmcnt(2)" ::: "memory");
    else asm volatile("s_waitcnt vmcnt(0)" ::: "memory");
}

#define PHASE_BARRIER() do { \
    asm volatile("s_waitcnt lgkmcnt(0)" ::: "memory"); \
    __builtin_amdgcn_sched_barrier(0); \
    __builtin_amdgcn_s_barrier(); \
    __builtin_amdgcn_sched_barrier(0); \
} while (0)

__device__ __forceinline__ int posw(int r, int c) { return r * H + (c ^ ((r & 7) << 3)); }

// Hybrid dual-path phase: 8 k-chunks of 32. Per chunk: matrix-0 fragment via
// global_load_lds ring slot (u&3), matrix-1 fragment via b128 global load into
// a 4-deep rolling register buffer. Both count in one vmcnt stream (2 ops per
// chunk, issued gload-then-regload, pinned by sched_barrier). vwait(4) per
// iteration = chunk u fully retired (in-order vmcnt retirement). Chunk u+3
// issued each iteration; stream continues across phases (gn/rn = next phase).
// LG = lgkm guard count = # of this-iteration ds_reads (2 if aD==aR else 3).
template <int P, int LG>
__device__ __forceinline__ void hybrid_phase(
    const ushort_t* __restrict__ gm, const ushort_t* __restrict__ rm,
    const ushort_t* __restrict__ gn, const ushort_t* __restrict__ rn,
    const ushort_t* aD, const ushort_t* aR,
    ushort_t* rw, int srcoff, int regoff, int boff, int kq, int sw,
    bf16x8 (&breg)[4], f32x4& accD, f32x4& accR) {
#pragma unroll
    for (int k = 0; k < 8; ++k) {
        const int u = P * 8 + k;
        if (P == 2) {
            if (k <= 5) vwait<4>();
            else if (k == 6) vwait<2>();
            else vwait<0>();
        } else {
            vwait<4>();
        }
        __builtin_amdgcn_sched_barrier(0);
        bf16x8 bD = *(const bf16x8*)(rw + (u & 3) * 512 + boff);
        const int ko = ((k << 5) + kq) ^ sw;
        bf16x8 aDv = *(const bf16x8*)(aD + ko);
        bf16x8 aRv;
        if constexpr (LG == 3) aRv = *(const bf16x8*)(aR + ko);
        else aRv = aDv;
        bf16x8 bR = breg[u & 3];
        if (u + 3 < 24) {
            if constexpr (LG == 2) asm volatile("s_waitcnt lgkmcnt(2)" ::: "memory");
            else                   asm volatile("s_waitcnt lgkmcnt(3)" ::: "memory");
            __builtin_amdgcn_sched_barrier(0);
            const int k3 = k + 3;
            const ushort_t* gsrc = (k3 < 8) ? gm : gn;
            const ushort_t* rsrc = (k3 < 8) ? rm : rn;
            const int cc = k3 & 7;
            gload16(gsrc + srcoff + (cc << 5), rw + ((u + 3) & 3) * 512);
            breg[(u + 3) & 3] = *(const bf16x8*)(rsrc + regoff + (cc << 5));
            __builtin_amdgcn_sched_barrier(0);
        }
        accD = __builtin_amdgcn_mfma_f32_16x16x32_bf16(aDv, bD, accD, 0, 0, 0);
        accR = __builtin_amdgcn_mfma_f32_16x16x32_bf16(aRv, bR, accR, 0, 0, 0);
    }
}

// register-path tile GEMM (small matrices), batched loads + sched fence
template <int NF, int STRA, int STRB>
__device__ __forceinline__ void gemm_one(const ushort_t* sA, const ushort_t* __restrict__ B0,
                                         int lane, int k0, f32x4& acc0) {
    const int row = lane & 15;
    const int kq = (lane >> 4) << 3;
    const int sw = (row & 7) << 3;
    bf16x8 b0[NF], a[NF];
    const ushort_t* bp0 = B0 + row * STRB + k0 + kq;
    const ushort_t* ap = sA + row * STRA;
#pragma unroll
    for (int i = 0; i < NF; i++) b0[i] = *(const bf16x8*)(bp0 + i * 32);
#pragma unroll
    for (int i = 0; i < NF; i++) a[i] = *(const bf16x8*)(ap + ((k0 + i * 32 + kq) ^ sw));
    __builtin_amdgcn_sched_barrier(0);
#pragma unroll
    for (int i = 0; i < NF; i++)
        acc0 = __builtin_amdgcn_mfma_f32_16x16x32_bf16(a[i], b0[i], acc0, 0, 0, 0);
}

__global__ __launch_bounds__(1024) void net_main(
    const float* __restrict__ x, const float* __restrict__ xd,
    const float* __restrict__ b1, const float* __restrict__ b2a,
    const float* __restrict__ b2b, const float* __restrict__ b3a,
    const float* __restrict__ b3s, const float* __restrict__ wout,
    const float* __restrict__ scalar, const ushort_t* __restrict__ ws,
    float* __restrict__ out) {
    extern __shared__ __align__(16) ushort_t smem[];
    ushort_t* sZ   = smem + U_Z;
    ushort_t* sY   = smem + U_Y;    // y1, then z1_3
    ushort_t* sZ12 = smem + U_Z12;
    ushort_t* sZ22 = smem + U_Z22;
    ushort_t* sZ23 = smem + U_Z23;  // z2_3, then FJ[0..1]
    ushort_t* sU   = smem + U_U;    // y2, then FJ[2..3]
    float* sXd = (float*)(smem + U_XD);
    float* sNB = (float*)(smem + U_NB);

    const int tid = threadIdx.x;
    const int wid = tid >> 6;     // 0..15
    const int lane = tid & 63;
    const int row16 = lane & 15;  // MFMA D column-within-tile
    const int rq = lane >> 4;     // MFMA D row = rq*4 + i
    const int R0 = blockIdx.x * RPB;
    const int n0 = wid * 16;      // this wave's 16-col tile
    const int kq = rq << 3;
    const int sw = (row16 & 7) << 3;

    ushort_t* rw = smem + U_RING + wid * 2048;
    const int nsrc = (wid << 4) + (lane >> 2);
    const int srcoff = nsrc * 256 + (((lane & 3) ^ (nsrc & 3)) << 3);
    const int boff = row16 * 32 + (kq ^ ((row16 & 3) << 3));
    const int regoff = (n0 + row16) * 256 + kq;
    const int arow = row16 * H;

    const ushort_t* gW2ab = ws + O_W2ab;
    const ushort_t* gW2bb = ws + O_W2bb;
    const ushort_t* gW3ab = ws + O_W3ab;
    const ushort_t* gW3aT = ws + O_W3aT;
    const ushort_t* gW2bT = ws + O_W2bT;
    const ushort_t* gW2aT = ws + O_W2aT;

    f32x4 y3keep;
    bf16x8 breg[4];

    // ---- P1: P1 loads, YY store, THEN fenced stream prologue (chunks 0..2);
    //      z = x@W1.T + b1 (y1 = z*z); z2_3 = x@W3s.T + b3s.
    {
        const ushort_t* w1p = ws + O_W1b + (n0 + row16) * 64 + kq;
        const ushort_t* w3p = ws + O_W3sb + (n0 + row16) * 64 + kq;
        bf16x8 pb0 = *(const bf16x8*)(w1p);
        bf16x8 pb1 = *(const bf16x8*)(w1p + 32);
        bf16x8 pb2 = *(const bf16x8*)(w3p);
        bf16x8 pb3 = *(const bf16x8*)(w3p + 32);
        const float* xg = x + (R0 + row16) * 64;
        float4 x0 = *(const float4*)(xg + kq);
        float4 x1 = *(const float4*)(xg + kq + 4);
        float4 x2 = *(const float4*)(xg + 32 + kq);
        float4 x3 = *(const float4*)(xg + 32 + kq + 4);
        int xr = tid >> 6, xc = tid & 63;
        float xdv = xd[(R0 + xr) * 64 + xc];
        float sc = scalar[0];
        out[YY_OFF + (R0 + xr) * 64 + xc] = sc;   // store pinned BEFORE prologue
        __builtin_amdgcn_sched_barrier(0);
        // stream prologue: chunks 0..2, pair order pinned (g then r each)
        gload16(gW2ab + srcoff, rw);
        __builtin_amdgcn_sched_barrier(0);
        breg[0] = *(const bf16x8*)(gW2bb + regoff);
        __builtin_amdgcn_sched_barrier(0);
        gload16(gW2ab + srcoff + 32, rw + 512);
        __builtin_amdgcn_sched_barrier(0);
        breg[1] = *(const bf16x8*)(gW2bb + regoff + 32);
        __builtin_amdgcn_sched_barrier(0);
        gload16(gW2ab + srcoff + 64, rw + 1024);
        __builtin_amdgcn_sched_barrier(0);
        breg[2] = *(const bf16x8*)(gW2bb + regoff + 64);
        __builtin_amdgcn_sched_barrier(0);
        // overlapped scalar work
        sXd[tid] = xdv;
        if (tid < RPB) sNB[tid] = 0.f;
        union { ushort_t u[8]; bf16x8 v; } A0, A1;
#pragma unroll
        for (int j = 0; j < 4; j++) {
            A0.u[j]     = f2bf(((const float*)&x0)[j]);
            A0.u[4 + j] = f2bf(((const float*)&x1)[j]);
            A1.u[j]     = f2bf(((const float*)&x2)[j]);
            A1.u[4 + j] = f2bf(((const float*)&x3)[j]);
        }
        f32x4 z = {0.f,0.f,0.f,0.f}, q = {0.f,0.f,0.f,0.f};
        z = __builtin_amdgcn_mfma_f32_16x16x32_bf16(A0.v, pb0, z, 0, 0, 0);
        z = __builtin_amdgcn_mfma_f32_16x16x32_bf16(A1.v, pb1, z, 0, 0, 0);
        q = __builtin_amdgcn_mfma_f32_16x16x32_bf16(A0.v, pb2, q, 0, 0, 0);
        q = __builtin_amdgcn_mfma_f32_16x16x32_bf16(A1.v, pb3, q, 0, 0, 0);
        int c = n0 + row16;
        float bz = b1[c], bs = b3s[c];
#pragma unroll
        for (int i = 0; i < 4; i++) {
            int r = rq * 4 + i;
            int p = posw(r, c);
            float za = z[i] + bz;
            sZ[p] = f2bf(za);
            sY[p] = f2bf(za * za);
            sZ23[p] = f2bf(q[i] + bs);
        }
    }
    PHASE_BARRIER();

    // ---- P2 (chunks 0..7): z1_2 = y1@W2a.T (DMA), z2_2 = y1@W2b.T (REG)
    {
        f32x4 aA = {0.f,0.f,0.f,0.f}, aB = {0.f,0.f,0.f,0.f};
        hybrid_phase<0, 2>(gW2ab, gW2bb, gW3ab, gW3aT, sY + arow, sY + arow,
                           rw, srcoff, regoff, boff, kq, sw, breg, aA, aB);
        int c = n0 + row16;
        float ba = b2a[c], bb = b2b[c];
#pragma unroll
        for (int i = 0; i < 4; i++) {
            int r = rq * 4 + i;
            int p = posw(r, c);
            float z12 = aA[i] + ba, z22 = aB[i] + bb;
            sZ12[p] = f2bf(z12);
            sZ22[p] = f2bf(z22);
            sU[p] = f2bf(z12 * z22);
        }
    }
    PHASE_BARRIER();

    // ---- P4 (chunks 8..15): z1_3 = y2@W3a.T (DMA); t = z2_3@(wout.w3a)T (REG)
    {
        f32x4 zz = {0.f,0.f,0.f,0.f}, tt = {0.f,0.f,0.f,0.f};
        hybrid_phase<1, 3>(gW3ab, gW3aT, gW2bT, gW2aT, sU + arow, sZ23 + arow,
                           rw, srcoff, regoff, boff, kq, sw, breg, zz, tt);
        int c = n0 + row16;
        float ba = b3a[c], wo = wout[c];
#pragma unroll
        for (int i = 0; i < 4; i++) {
            int r = rq * 4 + i;
            int p = posw(r, c);
            float z13 = zz[i] + ba;
            float z23 = bf2f(sZ23[p]);
            float y3 = z13 * z23;
            y3keep[i] = y3;                    // defer global store past the stream
            sY[p] = f2bf(z13);                 // sY now holds z1_3
            float t = tt[i];
            sZ12[p] = f2bf(t * bf2f(sZ12[p]));
            sZ22[p] = f2bf(t * bf2f(sZ22[p]));
            float v = wo * y3;
            v += __shfl_xor(v, 1);
            v += __shfl_xor(v, 2);
            v += __shfl_xor(v, 4);
            v += __shfl_xor(v, 8);
            if (row16 == 0) atomicAdd(&sNB[r], v);
        }
    }
    PHASE_BARRIER();

    // ---- P6 (chunks 16..23): p = tz1@W2bT (DMA) + tz2@W2aT (REG); c2 = 2*p*z
    {
        f32x4 pD = {0.f,0.f,0.f,0.f}, pR = {0.f,0.f,0.f,0.f};
        hybrid_phase<2, 3>(gW2bT, gW2aT, gW2bT, gW2aT, sZ12 + arow, sZ22 + arow,
                           rw, srcoff, regoff, boff, kq, sw, breg, pD, pR);
        int c = n0 + row16;
#pragma unroll
        for (int i = 0; i < 4; i++) {
            int r = rq * 4 + i;
            int p = posw(r, c);
            sZ[p] = f2bf(2.f * (pD[i] + pR[i]) * bf2f(sZ[p]));
        }
    }
    PHASE_BARRIER();

    // ---- P7: y3 stores; fj1 = z1_3@(wout.w3s)T, fj2 = c2@W1T
    {
        int c = n0 + row16;
#pragma unroll
        for (int i = 0; i < 4; i++)
            out[Y_OFF + (R0 + rq * 4 + i) * H + c] = y3keep[i];
        int mat = wid >> 3, kh = (wid >> 2) & 1, nt = wid & 3;
        const ushort_t* A = mat ? sZ : sY;
        const ushort_t* B = ws + (mat ? O_W1T : O_W3sT) + nt * 16 * H;
        f32x4 acc = {0.f,0.f,0.f,0.f};
        gemm_one<4, H, H>(A, B, lane, kh * 128, acc);
        float* F01 = (float*)sZ23;
        float* F23 = (float*)sU;
        float* dst = mat ? (F23 + kh * 1024) : (F01 + kh * 1024);
        int cc = nt * 16 + row16;
#pragma unroll
        for (int i = 0; i < 4; i++) dst[(rq * 4 + i) * 64 + cc] = acc[i];
    }
    PHASE_BARRIER();

    // ---- P8: bdot + nb writes
    {
        float* F0 = (float*)sZ23;
        float* F1 = F0 + 1024;
        float* F2 = (float*)sU;
        float* F3 = F2 + 1024;
        int r = tid >> 6, j = tid & 63;
        int e = r * 64 + j;
        float s = (F0[e] + F1[e] + F2[e] + F3[e]) * sXd[e];
        s += __shfl_xor(s, 1);
        s += __shfl_xor(s, 2);
        s += __shfl_xor(s, 4);
        s += __shfl_xor(s, 8);
        s += __shfl_xor(s, 16);
        s += __shfl_xor(s, 32);
        if (j == 0) out[BDOT_OFF + R0 + r] = s;
        if (tid < RPB) out[NB_OFF + R0 + tid] = sNB[tid];
    }
}

extern "C" void kernel_launch(void* const* d_in, const int* in_sizes, int n_in,
                              void* d_out, int out_size, void* d_ws, size_t ws_size,
                              hipStream_t stream) {
    (void)in_sizes; (void)n_in; (void)out_size; (void)ws_size;
    const float* x = (const float*)d_in[0];
    const float* xd = (const float*)d_in[1];
    const float* w1 = (const float*)d_in[2];
    const float* b1 = (const float*)d_in[3];
    const float* w2a = (const float*)d_in[4];
    const float* b2a = (const float*)d_in[5];
    const float* w2b = (const float*)d_in[6];
    const float* b2b = (const float*)d_in[7];
    const float* w3a = (const float*)d_in[8];
    const float* b3a = (const float*)d_in[9];
    const float* w3s = (const float*)d_in[10];
    const float* b3s = (const float*)d_in[11];
    const float* wout = (const float*)d_in[12];
    const float* scalar = (const float*)d_in[13];
    ushort_t* ws = (ushort_t*)d_ws;
    float* out = (float*)d_out;

    static bool attr_set = false;
    if (!attr_set) {
        hipFuncSetAttribute((const void*)net_main,
                            hipFuncAttributeMaxDynamicSharedMemorySize, SMEM_BYTES);
        attr_set = true;
    }

    prep_weights<<<112, 256, 0, stream>>>(w1, w2a, w2b, w3a, w3s, wout, ws);
    net_main<<<NBLK, 1024, SMEM_BYTES, stream>>>(x, xd, b1, b2a, b2b, b3a, b3s, wout, scalar, ws, out);
}

// Round 12
// 29.578 us; speedup vs baseline: 2.5863x; 1.1291x over previous
//
#include <hip/hip_runtime.h>

typedef unsigned short ushort_t;
typedef unsigned int uint_t;
typedef __bf16 bf16x8 __attribute__((ext_vector_type(8)));
typedef float f32x4 __attribute__((ext_vector_type(4)));

#define H 256
#define RPB 16      // batch rows per block
#define NBLK 256    // 4096 / RPB

// output layout (f32): [nb 4096][bdot 4096][y 4096*256][yy 4096*64]
#define NB_OFF 0
#define BDOT_OFF 4096
#define Y_OFF 8192
#define YY_OFF (8192 + 4096 * 256)

__device__ __forceinline__ ushort_t f2bf(float x) {
    union { float f; uint_t u; } c; c.f = x;
    uint_t r = (c.u + 0x7FFFu + ((c.u >> 16) & 1u)) >> 16;  // RNE
    return (ushort_t)r;
}
__device__ __forceinline__ float bf2f(ushort_t v) {
    union { uint_t u; float f; } c; c.u = ((uint_t)v) << 16;
    return c.f;
}

// ws layout (ushort units).
// Tiled streams: [16 n-tiles][8 k-chunks][1KB block in DMA lane order]
// block element (l*8+j) = W[t*16 + (l>>2)][c*32 + (((l&3)^((l>>2)&3))*8 + j)]
// (octet-XOR baked in so linear DMA + swizzled ds_read line up).
#define T_W2A  0        // w2a orig-orientation, tiled
#define T_W2B  65536
#define T_W3A  131072
#define T_W2BT 196608   // w2b transposed, tiled
#define T_W2AT 262144
#define T_W3AT 327680   // w3a transposed, wout-folded, tiled
#define O_W1b  393216   // [256][64] orig (P1 register path)
#define O_W1T  409600   // [64][256]
#define O_W3sb 425984   // [256][64]
#define O_W3sT 442368   // [64][256], wout folded

__global__ __launch_bounds__(256) void prep_weights(
    const float* __restrict__ w1, const float* __restrict__ w2a,
    const float* __restrict__ w2b, const float* __restrict__ w3a,
    const float* __restrict__ w3s, const float* __restrict__ wout,
    ushort_t* __restrict__ ws) {
    const int b = blockIdx.x;
    const int tid = threadIdx.x;
    if (b < 96) {
        // tiled streamed matrices: m = b>>4, n-tile t = b&15
        const int m = b >> 4, t = b & 15;
        const float* src; int dst; bool isT, scl;
        switch (m) {
            case 0: src = w2a; dst = T_W2A;  isT = false; scl = false; break;
            case 1: src = w2b; dst = T_W2B;  isT = false; scl = false; break;
            case 2: src = w3a; dst = T_W3A;  isT = false; scl = false; break;
            case 3: src = w2b; dst = T_W2BT; isT = true;  scl = false; break;
            case 4: src = w2a; dst = T_W2AT; isT = true;  scl = false; break;
            default: src = w3a; dst = T_W3AT; isT = true; scl = true;  break;
        }
        for (int idx = tid; idx < 4096; idx += 256) {
            int c = idx >> 9, rem = idx & 511;
            int l = rem >> 3, j = rem & 7;
            int r = l >> 2, o = (l & 3) ^ (r & 3);
            int gk = c * 32 + o * 8 + j;
            int row = t * 16 + r;
            float v = isT ? src[gk * 256 + row] : src[row * 256 + gk];
            if (scl) v *= wout[gk];
            ws[dst + t * 4096 + idx] = f2bf(v);
        }
        return;
    }
    // small matrices (w1, w3s): orig + transposed layouts
    __shared__ float tile[32][65];
    const float* src; int Oo, Ot, t; bool scl;
    if (b < 104) { src = w1;  Oo = O_W1b;  Ot = O_W1T;  t = b - 96;  scl = false; }
    else         { src = w3s; Oo = O_W3sb; Ot = O_W3sT; t = b - 104; scl = true;  }
    int r0 = t * 32;
    union pack8 { ushort_t u[8]; uint4 q; };
    {
        int r = tid >> 3, c8 = (tid & 7) << 3;
        const float* s = src + (r0 + r) * 64 + c8;
        pack8 p;
#pragma unroll
        for (int j = 0; j < 8; j++) { float v = s[j]; tile[r][c8 + j] = v; p.u[j] = f2bf(v); }
        *(uint4*)(ws + Oo + (r0 + r) * 64 + c8) = p.q;
    }
    __syncthreads();
    {
        int cc = tid >> 2, r8 = (tid & 3) << 3;
        pack8 p;
#pragma unroll
        for (int j = 0; j < 8; j++) {
            float v = tile[r8 + j][cc];
            if (scl) v *= wout[r0 + r8 + j];
            p.u[j] = f2bf(v);
        }
        *(uint4*)(ws + Ot + cc * 256 + r0 + r8) = p.q;
    }
}

// dynamic smem layout (ushort units)
#define RS 5            // ring slots per wave (512 ushorts = 1KB each)
#define RA 4            // units in flight per wave
#define U_RING 0        // 16 waves * 5 * 512 = 40960
#define U_Z    40960    // z -> c2 (in place)
#define U_Y    45056    // y1; later z1_3 (alias)
#define U_Z12  49152    // z1_2 -> t*z1_2
#define U_Z22  53248    // z2_2 -> t*z2_2
#define U_Z23  57344    // z2_3; later FJ[0..1] f32 (alias)
#define U_U    61440    // y2;   later FJ[2..3] f32 (alias)
#define U_XD   65536    // f32 [1024]
#define U_NB   69632    // f32 [16]
#define SMEM_USHORTS 69664
#define SMEM_BYTES (SMEM_USHORTS * 2)

__device__ __forceinline__ void gload16(const ushort_t* g, ushort_t* l) {
    __builtin_amdgcn_global_load_lds(
        (const __attribute__((address_space(1))) void*)g,
        (__attribute__((address_space(3))) void*)l, 16, 0, 0);
}

template <int N> __device__ __forceinline__ void vwait() {
    if constexpr (N == 3) asm volatile("s_waitcnt vmcnt(3)" ::: "memory");
    else if constexpr (N == 2) asm volatile("s_waitcnt vmcnt(2)" ::: "memory");
    else if constexpr (N == 1) asm volatile("s_waitcnt vmcnt(1)" ::: "memory");
    else asm volatile("s_waitcnt vmcnt(0)" ::: "memory");
}

#define PHASE_BARRIER() do { \
    asm volatile("s_waitcnt lgkmcnt(0)" ::: "memory"); \
    __builtin_amdgcn_sched_barrier(0); \
    __builtin_amdgcn_s_barrier(); \
    __builtin_amdgcn_sched_barrier(0); \
} while (0)

__device__ __forceinline__ int posw(int r, int c) { return r * H + (c ^ ((r & 7) << 3)); }

// Continuous-ring staged GEMM phase over 16 units (2 matrices x 8 k-chunks,
// interleaved). Unit u = P*16 + k; slot u%RS; restage u+RA into the slot read
// at u-1 (RS>RA), guarded lgkmcnt(2). Sources are TILED: unit (mat, chunk c')
// is the contiguous 1KB block at mat + (wid*8 + c')*512; per-lane addr is
// lane-linear (lane*8 ushorts) -> one fully-coalesced transaction per load.
// Per-block chunk rotation rot de-phases same-line L2 traffic across blocks;
// MFMA accumulation over chunks is order-independent.
template <int P, bool SUM>
__device__ __forceinline__ void ring_phase(
    const ushort_t* __restrict__ gm0, const ushort_t* __restrict__ gm1,
    const ushort_t* __restrict__ gn0, const ushort_t* __restrict__ gn1,
    const ushort_t* aP0, const ushort_t* aP1,
    ushort_t* rw, int wbase /* wid*4096 + lane*8 */, int rot,
    int boff, int kq, int sw, f32x4& acc0, f32x4& acc1) {
#pragma unroll
    for (int k = 0; k < 16; ++k) {
        const int u = P * 16 + k;
        if (P == 2) {
            if (k < 13) vwait<3>();
            else if (k == 13) vwait<2>();
            else if (k == 14) vwait<1>();
            else vwait<0>();
        } else {
            vwait<3>();
        }
        __builtin_amdgcn_sched_barrier(0);
        const int kc = ((k >> 1) + rot) & 7;  // rotated k-chunk (consume)
        bf16x8 b = *(const bf16x8*)(rw + (u % RS) * 512 + boff);
        const ushort_t* ap = (k & 1) ? aP1 : aP0;
        bf16x8 a = *(const bf16x8*)(ap + (((kc << 5) + kq) ^ sw));
        if (u + RA < 48) {
            asm volatile("s_waitcnt lgkmcnt(2)" ::: "memory");
            __builtin_amdgcn_sched_barrier(0);
            const int k4 = (u + RA) & 15;
            const bool nxt = (k + RA) >= 16;
            const ushort_t* g = nxt ? ((k4 & 1) ? gn1 : gn0)
                                    : ((k4 & 1) ? gm1 : gm0);
            const int cc = (((k4 >> 1)) + rot) & 7;
            gload16(g + wbase + (cc << 9), rw + ((u + RA) % RS) * 512);
        }
        acc0 = __builtin_amdgcn_mfma_f32_16x16x32_bf16(a, b, acc0, 0, 0, 0);
        if (!SUM && (k & 1)) { /* handled below */ }
        // route: parity 0 -> acc0 path already done; emulate R8 routing:
        (void)0;
        if (SUM) {
            // both parities accumulate into acc0 (done above) — nothing more
        }
        // For !SUM we need parity 1 in acc1; redo routing cleanly:
        // (the MFMA above applied to acc0 unconditionally for parity 0/SUM;
        //  for !SUM parity 1 we must NOT have touched acc0)
        static_assert(true, "");
    }
}

// NOTE: the routing in ring_phase above is replaced by ring_phase2 below,
// which reproduces R8's exact parity routing without dead paths.
template <int P, bool SUM>
__device__ __forceinline__ void ring_phase2(
    const ushort_t* __restrict__ gm0, const ushort_t* __restrict__ gm1,
    const ushort_t* __restrict__ gn0, const ushort_t* __restrict__ gn1,
    const ushort_t* aP0, const ushort_t* aP1,
    ushort_t* rw, int wbase, int rot,
    int boff, int kq, int sw, f32x4& acc0, f32x4& acc1) {
#pragma unroll
    for (int k = 0; k < 16; ++k) {
        const int u = P * 16 + k;
        if (P == 2) {
            if (k < 13) vwait<3>();
            else if (k == 13) vwait<2>();
            else if (k == 14) vwait<1>();
            else vwait<0>();
        } else {
            vwait<3>();
        }
        __builtin_amdgcn_sched_barrier(0);
        const int kc = ((k >> 1) + rot) & 7;
        bf16x8 b = *(const bf16x8*)(rw + (u % RS) * 512 + boff);
        const ushort_t* ap = (k & 1) ? aP1 : aP0;
        bf16x8 a = *(const bf16x8*)(ap + (((kc << 5) + kq) ^ sw));
        if (u + RA < 48) {
            asm volatile("s_waitcnt lgkmcnt(2)" ::: "memory");
            __builtin_amdgcn_sched_barrier(0);
            const int k4 = (u + RA) & 15;
            const bool nxt = (k + RA) >= 16;
            const ushort_t* g = nxt ? ((k4 & 1) ? gn1 : gn0)
                                    : ((k4 & 1) ? gm1 : gm0);
            const int cc = ((k4 >> 1) + rot) & 7;
            gload16(g + wbase + (cc << 9), rw + ((u + RA) % RS) * 512);
        }
        if (SUM)
            acc0 = __builtin_amdgcn_mfma_f32_16x16x32_bf16(a, b, acc0, 0, 0, 0);
        else if ((k & 1) == 0)
            acc0 = __builtin_amdgcn_mfma_f32_16x16x32_bf16(a, b, acc0, 0, 0, 0);
        else
            acc1 = __builtin_amdgcn_mfma_f32_16x16x32_bf16(a, b, acc1, 0, 0, 0);
    }
}

// register-path tile GEMM (small matrices), batched loads + sched fence
template <int NF, int STRA, int STRB>
__device__ __forceinline__ void gemm_one(const ushort_t* sA, const ushort_t* __restrict__ B0,
                                         int lane, int k0, f32x4& acc0) {
    const int row = lane & 15;
    const int kq = (lane >> 4) << 3;
    const int sw = (row & 7) << 3;
    bf16x8 b0[NF], a[NF];
    const ushort_t* bp0 = B0 + row * STRB + k0 + kq;
    const ushort_t* ap = sA + row * STRA;
#pragma unroll
    for (int i = 0; i < NF; i++) b0[i] = *(const bf16x8*)(bp0 + i * 32);
#pragma unroll
    for (int i = 0; i < NF; i++) a[i] = *(const bf16x8*)(ap + ((k0 + i * 32 + kq) ^ sw));
    __builtin_amdgcn_sched_barrier(0);
#pragma unroll
    for (int i = 0; i < NF; i++)
        acc0 = __builtin_amdgcn_mfma_f32_16x16x32_bf16(a[i], b0[i], acc0, 0, 0, 0);
}

__global__ __launch_bounds__(1024) void net_main(
    const float* __restrict__ x, const float* __restrict__ xd,
    const float* __restrict__ b1, const float* __restrict__ b2a,
    const float* __restrict__ b2b, const float* __restrict__ b3a,
    const float* __restrict__ b3s, const float* __restrict__ wout,
    const float* __restrict__ scalar, const ushort_t* __restrict__ ws,
    float* __restrict__ out) {
    extern __shared__ __align__(16) ushort_t smem[];
    ushort_t* sZ   = smem + U_Z;
    ushort_t* sY   = smem + U_Y;    // y1, then z1_3
    ushort_t* sZ12 = smem + U_Z12;
    ushort_t* sZ22 = smem + U_Z22;
    ushort_t* sZ23 = smem + U_Z23;  // z2_3, then FJ[0..1]
    ushort_t* sU   = smem + U_U;    // y2, then FJ[2..3]
    float* sXd = (float*)(smem + U_XD);
    float* sNB = (float*)(smem + U_NB);

    const int tid = threadIdx.x;
    const int wid = tid >> 6;     // 0..15
    const int lane = tid & 63;
    const int row16 = lane & 15;  // MFMA D column-within-tile
    const int rq = lane >> 4;     // MFMA D row = rq*4 + i
    const int R0 = blockIdx.x * RPB;
    const int n0 = wid * 16;      // this wave's 16-col tile
    const int kq = rq << 3;
    const int sw = (row16 & 7) << 3;
    const int rot = blockIdx.x & 7;   // k-chunk rotation (L2 de-phasing)

    ushort_t* rw = smem + U_RING + wid * (RS * 512);
    const int wbase = wid * 4096 + lane * 8;   // per-lane addr inside a tiled unit
    const int boff = row16 * 32 + (kq ^ ((row16 & 3) << 3));
    const int arow = row16 * H;

    const ushort_t* tW2A  = ws + T_W2A;
    const ushort_t* tW2B  = ws + T_W2B;
    const ushort_t* tW3A  = ws + T_W3A;
    const ushort_t* tW3AT = ws + T_W3AT;
    const ushort_t* tW2BT = ws + T_W2BT;
    const ushort_t* tW2AT = ws + T_W2AT;

    f32x4 y3keep;

    // ---- P1: stores/loads first (oldest), ring prologue last (newest);
    //      z = x@W1.T + b1 (y1 = z*z); z2_3 = x@W3s.T + b3s.
    {
        const ushort_t* w1p = ws + O_W1b + (n0 + row16) * 64 + kq;
        const ushort_t* w3p = ws + O_W3sb + (n0 + row16) * 64 + kq;
        bf16x8 pb0 = *(const bf16x8*)(w1p);
        bf16x8 pb1 = *(const bf16x8*)(w1p + 32);
        bf16x8 pb2 = *(const bf16x8*)(w3p);
        bf16x8 pb3 = *(const bf16x8*)(w3p + 32);
        const float* xg = x + (R0 + row16) * 64;
        float4 x0 = *(const float4*)(xg + kq);
        float4 x1 = *(const float4*)(xg + kq + 4);
        float4 x2 = *(const float4*)(xg + 32 + kq);
        float4 x3 = *(const float4*)(xg + 32 + kq + 4);
        int xr = tid >> 6, xc = tid & 63;
        float xdv = xd[(R0 + xr) * 64 + xc];
        float sc = scalar[0];
        out[YY_OFF + (R0 + xr) * 64 + xc] = sc;   // store pinned before prologue
        __builtin_amdgcn_sched_barrier(0);
        // ring prologue: units 0..3 = (W2A,rc0),(W2B,rc0),(W2A,rc1),(W2B,rc1)
        {
            const int rc0 = rot, rc1 = (rot + 1) & 7;
            gload16(tW2A + wbase + (rc0 << 9), rw);
            gload16(tW2B + wbase + (rc0 << 9), rw + 512);
            gload16(tW2A + wbase + (rc1 << 9), rw + 1024);
            gload16(tW2B + wbase + (rc1 << 9), rw + 1536);
        }
        __builtin_amdgcn_sched_barrier(0);
        sXd[tid] = xdv;
        if (tid < RPB) sNB[tid] = 0.f;
        union { ushort_t u[8]; bf16x8 v; } A0, A1;
#pragma unroll
        for (int j = 0; j < 4; j++) {
            A0.u[j]     = f2bf(((const float*)&x0)[j]);
            A0.u[4 + j] = f2bf(((const float*)&x1)[j]);
            A1.u[j]     = f2bf(((const float*)&x2)[j]);
            A1.u[4 + j] = f2bf(((const float*)&x3)[j]);
        }
        f32x4 z = {0.f,0.f,0.f,0.f}, q = {0.f,0.f,0.f,0.f};
        z = __builtin_amdgcn_mfma_f32_16x16x32_bf16(A0.v, pb0, z, 0, 0, 0);
        z = __builtin_amdgcn_mfma_f32_16x16x32_bf16(A1.v, pb1, z, 0, 0, 0);
        q = __builtin_amdgcn_mfma_f32_16x16x32_bf16(A0.v, pb2, q, 0, 0, 0);
        q = __builtin_amdgcn_mfma_f32_16x16x32_bf16(A1.v, pb3, q, 0, 0, 0);
        int c = n0 + row16;
        float bz = b1[c], bs = b3s[c];
#pragma unroll
        for (int i = 0; i < 4; i++) {
            int r = rq * 4 + i;
            int p = posw(r, c);
            float za = z[i] + bz;
            sZ[p] = f2bf(za);
            sY[p] = f2bf(za * za);
            sZ23[p] = f2bf(q[i] + bs);
        }
    }
    PHASE_BARRIER();

    // ---- P2 (ring 0..15): z1_2 = y1@W2a.T, z2_2 = y1@W2b.T; y2 -> sU
    {
        f32x4 aA = {0.f,0.f,0.f,0.f}, aB = {0.f,0.f,0.f,0.f};
        ring_phase2<0, false>(tW2A, tW2B, tW3A, tW3AT, sY + arow, sY + arow,
                              rw, wbase, rot, boff, kq, sw, aA, aB);
        int c = n0 + row16;
        float ba = b2a[c], bb = b2b[c];
#pragma unroll
        for (int i = 0; i < 4; i++) {
            int r = rq * 4 + i;
            int p = posw(r, c);
            float z12 = aA[i] + ba, z22 = aB[i] + bb;
            sZ12[p] = f2bf(z12);
            sZ22[p] = f2bf(z22);
            sU[p] = f2bf(z12 * z22);
        }
    }
    PHASE_BARRIER();

    // ---- P4 (ring 16..31): z1_3 = y2@W3a.T + b3a; t = z2_3@(wout.w3a)T
    {
        f32x4 zz = {0.f,0.f,0.f,0.f}, tt = {0.f,0.f,0.f,0.f};
        ring_phase2<1, false>(tW3A, tW3AT, tW2BT, tW2AT, sU + arow, sZ23 + arow,
                              rw, wbase, rot, boff, kq, sw, zz, tt);
        int c = n0 + row16;
        float ba = b3a[c], wo = wout[c];
#pragma unroll
        for (int i = 0; i < 4; i++) {
            int r = rq * 4 + i;
            int p = posw(r, c);
            float z13 = zz[i] + ba;
            float z23 = bf2f(sZ23[p]);
            float y3 = z13 * z23;
            y3keep[i] = y3;                    // defer global store past the ring
            sY[p] = f2bf(z13);                 // sY now holds z1_3
            float t = tt[i];
            sZ12[p] = f2bf(t * bf2f(sZ12[p]));
            sZ22[p] = f2bf(t * bf2f(sZ22[p]));
            float v = wo * y3;
            v += __shfl_xor(v, 1);
            v += __shfl_xor(v, 2);
            v += __shfl_xor(v, 4);
            v += __shfl_xor(v, 8);
            if (row16 == 0) atomicAdd(&sNB[r], v);
        }
    }
    PHASE_BARRIER();

    // ---- P6 (ring 32..47): p = tz1@W2bT + tz2@W2aT ; c2 = 2*p*z
    {
        f32x4 pp = {0.f,0.f,0.f,0.f}, dummy = {0.f,0.f,0.f,0.f};
        ring_phase2<2, true>(tW2BT, tW2AT, tW2BT, tW2AT, sZ12 + arow, sZ22 + arow,
                             rw, wbase, rot, boff, kq, sw, pp, dummy);
        int c = n0 + row16;
#pragma unroll
        for (int i = 0; i < 4; i++) {
            int r = rq * 4 + i;
            int p = posw(r, c);
            sZ[p] = f2bf(2.f * pp[i] * bf2f(sZ[p]));
        }
    }
    PHASE_BARRIER();

    // ---- P7: y3 stores; fj1 = z1_3@(wout.w3s)T, fj2 = c2@W1T
    {
        int c = n0 + row16;
#pragma unroll
        for (int i = 0; i < 4; i++)
            out[Y_OFF + (R0 + rq * 4 + i) * H + c] = y3keep[i];
        int mat = wid >> 3, kh = (wid >> 2) & 1, nt = wid & 3;
        const ushort_t* A = mat ? sZ : sY;
        const ushort_t* B = ws + (mat ? O_W1T : O_W3sT) + nt * 16 * H;
        f32x4 acc = {0.f,0.f,0.f,0.f};
        gemm_one<4, H, H>(A, B, lane, kh * 128, acc);
        float* F01 = (float*)sZ23;
        float* F23 = (float*)sU;
        float* dst = mat ? (F23 + kh * 1024) : (F01 + kh * 1024);
        int cc = nt * 16 + row16;
#pragma unroll
        for (int i = 0; i < 4; i++) dst[(rq * 4 + i) * 64 + cc] = acc[i];
    }
    PHASE_BARRIER();

    // ---- P8: bdot + nb writes
    {
        float* F0 = (float*)sZ23;
        float* F1 = F0 + 1024;
        float* F2 = (float*)sU;
        float* F3 = F2 + 1024;
        int r = tid >> 6, j = tid & 63;
        int e = r * 64 + j;
        float s = (F0[e] + F1[e] + F2[e] + F3[e]) * sXd[e];
        s += __shfl_xor(s, 1);
        s += __shfl_xor(s, 2);
        s += __shfl_xor(s, 4);
        s += __shfl_xor(s, 8);
        s += __shfl_xor(s, 16);
        s += __shfl_xor(s, 32);
        if (j == 0) out[BDOT_OFF + R0 + r] = s;
        if (tid < RPB) out[NB_OFF + R0 + tid] = sNB[tid];
    }
}

extern "C" void kernel_launch(void* const* d_in, const int* in_sizes, int n_in,
                              void* d_out, int out_size, void* d_ws, size_t ws_size,
                              hipStream_t stream) {
    (void)in_sizes; (void)n_in; (void)out_size; (void)ws_size;
    const float* x = (const float*)d_in[0];
    const float* xd = (const float*)d_in[1];
    const float* w1 = (const float*)d_in[2];
    const float* b1 = (const float*)d_in[3];
    const float* w2a = (const float*)d_in[4];
    const float* b2a = (const float*)d_in[5];
    const float* w2b = (const float*)d_in[6];
    const float* b2b = (const float*)d_in[7];
    const float* w3a = (const float*)d_in[8];
    const float* b3a = (const float*)d_in[9];
    const float* w3s = (const float*)d_in[10];
    const float* b3s = (const float*)d_in[11];
    const float* wout = (const float*)d_in[12];
    const float* scalar = (const float*)d_in[13];
    ushort_t* ws = (ushort_t*)d_ws;
    float* out = (float*)d_out;

    static bool attr_set = false;
    if (!attr_set) {
        hipFuncSetAttribute((const void*)net_main,
                            hipFuncAttributeMaxDynamicSharedMemorySize, SMEM_BYTES);
        attr_set = true;
    }

    prep_weights<<<112, 256, 0, stream>>>(w1, w2a, w2b, w3a, w3s, wout, ws);
    net_main<<<NBLK, 1024, SMEM_BYTES, stream>>>(x, xd, b1, b2a, b2b, b3a, b3s, wout, scalar, ws, out);
}